// Round 5
// baseline (254.434 us; speedup 1.0000x reference)
//
#include <hip/hip_runtime.h>
#include <hip/hip_bf16.h>

// B=8, S=2048, C=512 single-head attention + residual, fp32 I/O.
// out = softmax(QK^T) V + x,  Q/K/V = x@W^T + b  (no 1/sqrt(dk)).
//
// Round 5:
//  - flash_attn_v4: QK^T with r=2 q-reuse (wave = 32q x 16keys, Q in regs,
//    each K-frag feeds 2 MFMAs) -> QK^T LDS reads halved vs v3.
//    PV (wave = 64q x 64d), staging, no-max-shift softmax unchanged.
//  - qkv_gemm: Q/K epilogue now goes through the LDS transpose path
//    (stride 272 for aligned b128) -> coalesced dwordx4 global stores.
//
// ws layout (total 68,687,872 B):
//   Wb    bf16 [1536][512]              @ 0
//   biasc f32  [1536]                   @ 1,572,864
//   Xb    bf16 [16384][512]             @ 1,579,008
//   Qb    bf16 [16384][512]             @ 18,356,224
//   Kb    bf16 [16384][512]             @ 35,133,440
//   Vt    bf16 [8][512][2048]           @ 51,910,656

typedef __bf16 bf16_t;
typedef bf16_t bf16x8 __attribute__((ext_vector_type(8)));
typedef float floatx4 __attribute__((ext_vector_type(4)));

#define MFMA16(a, b, c) __builtin_amdgcn_mfma_f32_16x16x32_bf16((a), (b), (c), 0, 0, 0)
// Ks 65536 + Vs 65536 + Ps 64*144=9216 + lpart 64*4*4=1024
#define FLASH_LDS 141312

__device__ __forceinline__ void gload16(const void* g, void* l) {
    __builtin_amdgcn_global_load_lds((const __attribute__((address_space(1))) void*)g,
                                     (__attribute__((address_space(3))) void*)l, 16, 0, 0);
}

__device__ __forceinline__ float wave16_sum(float v) {
    v += __shfl_xor(v, 1);
    v += __shfl_xor(v, 2);
    v += __shfl_xor(v, 4);
    v += __shfl_xor(v, 8);
    return v;
}

// ---------------------------------------------------------------------------
// Kernel 1: convert X -> bf16 (blocks 0..4095), W/b -> bf16/f32 (4096..4863).
// ---------------------------------------------------------------------------
__global__ void convert_in(const float* __restrict__ X,
                           const float* __restrict__ Wq, const float* __restrict__ Wk,
                           const float* __restrict__ Wv, const float* __restrict__ bq,
                           const float* __restrict__ bk, const float* __restrict__ bv,
                           bf16_t* __restrict__ Xb, bf16_t* __restrict__ Wb,
                           float* __restrict__ biasc) {
    int bid = blockIdx.x, tid = threadIdx.x;
    if (bid < 4096) {
        size_t e0 = ((size_t)bid * 256 + tid) * 8;
        float4 f0 = *(const float4*)(X + e0);
        float4 f1 = *(const float4*)(X + e0 + 4);
        bf16x8 o;
        o[0] = (bf16_t)f0.x; o[1] = (bf16_t)f0.y; o[2] = (bf16_t)f0.z; o[3] = (bf16_t)f0.w;
        o[4] = (bf16_t)f1.x; o[5] = (bf16_t)f1.y; o[6] = (bf16_t)f1.z; o[7] = (bf16_t)f1.w;
        *(bf16x8*)(Xb + e0) = o;
    } else {
        int idx = (bid - 4096) * 256 + tid;       // [0, 196608)
        int e0 = idx * 4;
        int row = e0 >> 9, c = e0 & 511;
        const float* src;
        if (row < 512)       src = Wq + row * 512;
        else if (row < 1024) src = Wk + (row - 512) * 512;
        else                 src = Wv + (row - 1024) * 512;
        float4 v = *(const float4*)(src + c);
        Wb[e0 + 0] = (bf16_t)v.x;
        Wb[e0 + 1] = (bf16_t)v.y;
        Wb[e0 + 2] = (bf16_t)v.z;
        Wb[e0 + 3] = (bf16_t)v.w;
        if (idx < 1536) {
            float b;
            if (idx < 512)       b = bq[idx];
            else if (idx < 1024) b = bk[idx - 512];
            else                 b = bv[idx - 1024];
            biasc[idx] = b;
        }
    }
}

// ---------------------------------------------------------------------------
// Kernel 2: QKV GEMM, C[16384][1536] = Xb * Wb^T + bias.
// 128x128 tile, BK=64, global_load_lds 16B staging, XOR-swizzled LDS.
// ALL tiles (Q, K, V) now route the epilogue through an LDS transpose buffer
// (row stride 272 B = 17 granules -> 16B-aligned, bank-spread) so every
// global store is a coalesced dwordx4.
// ---------------------------------------------------------------------------
__global__ __launch_bounds__(256, 2)
void qkv_gemm(const bf16_t* __restrict__ Xb, const bf16_t* __restrict__ Wb,
              const float* __restrict__ biasc, bf16_t* __restrict__ Q,
              bf16_t* __restrict__ K, bf16_t* __restrict__ Vt) {
    __shared__ int4 smem4[2560];          // 40960 B
    char* As = (char*)smem4;              // 16384 B: 128 rows x 8 chunks(16B)
    char* Bs = (char*)smem4 + 16384;      // 16384 B
    char* Ctile = (char*)smem4;           // 34816 B (reused after barrier)

    const int tid = threadIdx.x;
    const int l = tid & 63, w = tid >> 6;
    const int lane16 = l & 15, lq = l >> 4;
    const int klo = lane16 & 7;
    const int m0 = (blockIdx.x & 127) << 7;
    const int n0 = (blockIdx.x >> 7) << 7;
    const int wm = (w >> 1) << 6, wn = (w & 1) << 6;
    const int srow = l >> 3;
    const int sc8 = (l & 7) ^ srow;

    floatx4 acc[4][4];
#pragma unroll
    for (int a = 0; a < 4; ++a)
#pragma unroll
        for (int bb = 0; bb < 4; ++bb) acc[a][bb] = (floatx4){0.f, 0.f, 0.f, 0.f};

    for (int it = 0; it < 8; ++it) {
        __syncthreads();
#pragma unroll
        for (int j = 0; j < 4; ++j) {
            int seg = j * 4 + w;
            int row = seg * 8 + srow;
            gload16(Xb + (size_t)(m0 + row) * 512 + it * 64 + sc8 * 8, As + seg * 1024);
            gload16(Wb + (size_t)(n0 + row) * 512 + it * 64 + sc8 * 8, Bs + seg * 1024);
        }
        __syncthreads();
#pragma unroll
        for (int kst = 0; kst < 2; ++kst) {
            bf16x8 afr[4], bfr[4];
#pragma unroll
            for (int mt = 0; mt < 4; ++mt)
                afr[mt] = *(const bf16x8*)(As + (wm + mt * 16 + lane16) * 128 +
                                           ((kst * 4 + lq) ^ klo) * 16);
#pragma unroll
            for (int nt = 0; nt < 4; ++nt)
                bfr[nt] = *(const bf16x8*)(Bs + (wn + nt * 16 + lane16) * 128 +
                                           ((kst * 4 + lq) ^ klo) * 16);
#pragma unroll
            for (int mt = 0; mt < 4; ++mt)
#pragma unroll
                for (int nt = 0; nt < 4; ++nt)
                    acc[mt][nt] = MFMA16(afr[mt], bfr[nt], acc[mt][nt]);
        }
    }

    float bias_v[4];
#pragma unroll
    for (int nt = 0; nt < 4; ++nt) bias_v[nt] = biasc[n0 + wn + nt * 16 + lane16];

    __syncthreads();   // done reading As/Bs; Ctile may overwrite

    if (n0 < 1024) {
        // Q or K tile: Ctile[row=m][col] then coalesced row-major stores
#pragma unroll
        for (int mt = 0; mt < 4; ++mt)
#pragma unroll
            for (int nt = 0; nt < 4; ++nt)
#pragma unroll
                for (int i = 0; i < 4; ++i) {
                    int rl = wm + mt * 16 + lq * 4 + i;        // row within 128
                    int cl = wn + nt * 16 + lane16;            // col within 128
                    *(bf16_t*)(Ctile + rl * 272 + cl * 2) =
                        (bf16_t)(acc[mt][nt][i] + bias_v[nt]);
                }
        __syncthreads();
        bf16_t* Dst = (n0 < 512) ? Q : K;
        const int coff = (n0 < 512) ? n0 : (n0 - 512);
#pragma unroll
        for (int j = 0; j < 8; ++j) {
            int slot = j * 256 + tid;      // 2048 slots: 128 rows x 16 chunks
            int row = slot >> 4, c = slot & 15;
            *(int4*)(Dst + (size_t)(m0 + row) * 512 + coff + c * 8) =
                *(const int4*)(Ctile + row * 272 + c * 16);
        }
    } else {
        // V tile: Ctile[row=d][col=s] (transpose), coalesced Vt stores
#pragma unroll
        for (int mt = 0; mt < 4; ++mt)
#pragma unroll
            for (int nt = 0; nt < 4; ++nt)
#pragma unroll
                for (int i = 0; i < 4; ++i) {
                    int dl = wn + nt * 16 + lane16;            // d within 128
                    int sl = wm + mt * 16 + lq * 4 + i;        // s within 128
                    *(bf16_t*)(Ctile + dl * 272 + sl * 2) =
                        (bf16_t)(acc[mt][nt][i] + bias_v[nt]);
                }
        __syncthreads();
        const int bb = m0 >> 11, s0 = m0 & 2047, dbase = n0 - 1024;
#pragma unroll
        for (int j = 0; j < 8; ++j) {
            int slot = j * 256 + tid;      // 2048 slots: 128 d x 16 chunks
            int dd = slot >> 4, c = slot & 15;
            *(int4*)(Vt + (size_t)(bb * 512 + dbase + dd) * 2048 + s0 + c * 8) =
                *(const int4*)(Ctile + dd * 272 + c * 16);
        }
    }
}

// ---------------------------------------------------------------------------
// Kernel 3: flash attention v4 + residual. 256 blocks (b = bid&7 -> XCD
// affinity), 512 threads = 8 waves. Block = 64 q-rows, iter = 64 keys.
//  QK^T: wave (qh = w>>2, kq = w&3) computes S[32 q][16 keys], full k=512.
//        Q for both 16-row subtiles in registers; each K-frag LDS read feeds
//        2 MFMAs (r=2 reuse) -> QK^T LDS traffic halved vs v3.
//  softmax: p = exp(s), no max shift; l = running per-lane sum.
//  PV:   wave w owns d-slice w*64..+64 for ALL 64 q rows (unchanged).
// ---------------------------------------------------------------------------
__global__ __launch_bounds__(512, 2)
void flash_attn_v4(const bf16_t* __restrict__ Q, const bf16_t* __restrict__ K,
                   const bf16_t* __restrict__ Vt, const float* __restrict__ X,
                   float* __restrict__ Out) {
    extern __shared__ char smem[];
    char* Ks = smem;                   // 65536: 64 keys x 64 chunks(16B), swizzled
    char* Vs = smem + 65536;           // 65536: 512 d x 8 chunks(16B), swizzled
    char* Ps = smem + 131072;          // 9216: 64 rows x 144 B (128 data + 16 pad)
    float* lpart = (float*)(smem + 140288);   // 64 rows x 4 kq

    const int tid = threadIdx.x;
    const int l = tid & 63, w = tid >> 6;
    const int lane16 = l & 15, lq = l >> 4;
    const int qh = w >> 2, kq = w & 3;         // QK^T role
    const int dbase = w << 6;                  // PV d-slice
    const int b = blockIdx.x & 7;
    const int q0 = (blockIdx.x >> 3) << 6;

    const bf16_t* Kbase = K + (size_t)b * 2048 * 512;
    const bf16_t* Vbase = Vt + (size_t)b * 512 * 2048;

    // stage K_0: 64 segs (keys) x 1KB, 8 per wave, source-chunk swizzle ^seg
#pragma unroll
    for (int j = 0; j < 8; ++j) {
        int seg = j * 8 + w;
        int c = (l & ~7) | ((l & 7) ^ (seg & 7));
        gload16(Kbase + (size_t)seg * 512 + c * 8, Ks + seg * 1024);
    }

    // Q fragments for TWO 16-row subtiles: rows q0+qh*32+{0..15, 16..31}
    bf16x8 qf0[16], qf1[16];
    const bf16_t* Qr0 = Q + (size_t)(b * 2048 + q0 + qh * 32 + lane16) * 512 + lq * 8;
#pragma unroll
    for (int kst = 0; kst < 16; ++kst) {
        qf0[kst] = *(const bf16x8*)(Qr0 + kst * 32);
        qf1[kst] = *(const bf16x8*)(Qr0 + 16 * 512 + kst * 32);
    }

    floatx4 o[16];                     // [qgi][dg]: rows qgi*16.., cols dbase+dg*16..
#pragma unroll
    for (int t = 0; t < 16; ++t) o[t] = (floatx4){0.f, 0.f, 0.f, 0.f};
    float ls0[4] = {0.f, 0.f, 0.f, 0.f};
    float ls1[4] = {0.f, 0.f, 0.f, 0.f};
    const float L2E = 1.4426950408889634f;

    const int key = kq * 16 + lane16;          // this lane's key within tile
    const char* kptr = Ks + key * 1024;
    const int k7 = key & 7;

    __syncthreads();   // K_0 staged

    for (int kt = 0; kt < 32; ++kt) {
        // issue V_kt staging (overlaps QK^T): 64 segs x (8 d x 8 key-chunks)
        {
            const bf16_t* Vsrc = Vbase + kt * 64;
#pragma unroll
            for (int j = 0; j < 8; ++j) {
                int seg = j * 8 + w;
                int d = seg * 8 + (l >> 3);
                int c = (l & 7) ^ (l >> 3);
                gload16(Vsrc + (size_t)d * 2048 + c * 8, Vs + seg * 1024);
            }
        }
        // ---- QK^T: 32 q rows x 16 keys, k=512, K-frag reuse x2 ----
        floatx4 s0a = (floatx4){0.f, 0.f, 0.f, 0.f};
        floatx4 s0b = (floatx4){0.f, 0.f, 0.f, 0.f};
        floatx4 s1a = (floatx4){0.f, 0.f, 0.f, 0.f};
        floatx4 s1b = (floatx4){0.f, 0.f, 0.f, 0.f};
#pragma unroll
        for (int kst = 0; kst < 16; kst += 2) {
            int i0 = kst * 4 + lq;
            int i1 = i0 + 4;
            int p0 = (i0 & ~7) | ((i0 & 7) ^ k7);
            int p1 = (i1 & ~7) | ((i1 & 7) ^ k7);
            bf16x8 kb0 = *(const bf16x8*)(kptr + p0 * 16);
            bf16x8 kb1 = *(const bf16x8*)(kptr + p1 * 16);
            s0a = MFMA16(qf0[kst], kb0, s0a);
            s0b = MFMA16(qf0[kst + 1], kb1, s0b);
            s1a = MFMA16(qf1[kst], kb0, s1a);
            s1b = MFMA16(qf1[kst + 1], kb1, s1b);
        }
        // ---- softmax (no max shift): p = exp(s), write P, accumulate l ----
#pragma unroll
        for (int i = 0; i < 4; ++i) {
            float p0 = __builtin_exp2f((s0a[i] + s0b[i]) * L2E);
            float p1 = __builtin_exp2f((s1a[i] + s1b[i]) * L2E);
            ls0[i] += p0;
            ls1[i] += p1;
            int row0 = qh * 32 + lq * 4 + i;
            *(bf16_t*)(Ps + row0 * 144 + key * 2) = (bf16_t)p0;
            *(bf16_t*)(Ps + (row0 + 16) * 144 + key * 2) = (bf16_t)p1;
        }
        __syncthreads();   // barrier 1: V_kt staged, P visible, Ks free

        // issue K_{kt+1} staging (overlaps PV)
        if (kt < 31) {
            const bf16_t* Ksrc = Kbase + (size_t)(kt + 1) * 64 * 512;
#pragma unroll
            for (int j = 0; j < 8; ++j) {
                int seg = j * 8 + w;
                int c = (l & ~7) | ((l & 7) ^ (seg & 7));
                gload16(Ksrc + (size_t)seg * 512 + c * 8, Ks + seg * 1024);
            }
        }
        // ---- PV: O[64 q x 64 d slice] += P[64x64] * V^T ----
#pragma unroll
        for (int kk = 0; kk < 2; ++kk) {
            bf16x8 pa[4];
#pragma unroll
            for (int qgi = 0; qgi < 4; ++qgi)
                pa[qgi] = *(const bf16x8*)(Ps + (qgi * 16 + lane16) * 144 + kk * 64 + lq * 16);
#pragma unroll
            for (int dg = 0; dg < 4; ++dg) {
                int d = dbase + dg * 16 + lane16;
                int pos = (kk * 4 + lq) ^ (d & 7);
                bf16x8 vb = *(const bf16x8*)(Vs + d * 128 + pos * 16);
#pragma unroll
                for (int qgi = 0; qgi < 4; ++qgi)
                    o[qgi * 4 + dg] = MFMA16(pa[qgi], vb, o[qgi * 4 + dg]);
            }
        }
        __syncthreads();   // barrier 2: K_{kt+1} staged, Vs/Ps free
    }

    // epilogue: reduce l over lane16 (16 keys/wave) -> lpart[row][kq]
#pragma unroll
    for (int i = 0; i < 4; ++i) {
        float s0 = wave16_sum(ls0[i]);
        float s1 = wave16_sum(ls1[i]);
        if (lane16 == 0) {
            lpart[(qh * 32 + lq * 4 + i) * 4 + kq] = s0;
            lpart[(qh * 32 + 16 + lq * 4 + i) * 4 + kq] = s1;
        }
    }
    __syncthreads();

#pragma unroll
    for (int qgi = 0; qgi < 4; ++qgi) {
        float rinv[4];
#pragma unroll
        for (int i = 0; i < 4; ++i) {
            int row = qgi * 16 + lq * 4 + i;
            float4 l4 = *(float4*)&lpart[row * 4];
            rinv[i] = 1.0f / (l4.x + l4.y + l4.z + l4.w);
        }
#pragma unroll
        for (int dg = 0; dg < 4; ++dg) {
            int d = dbase + dg * 16 + lane16;
#pragma unroll
            for (int i = 0; i < 4; ++i) {
                int row = q0 + qgi * 16 + lq * 4 + i;
                size_t g = (size_t)(b * 2048 + row) * 512 + d;
                Out[g] = o[qgi * 4 + dg][i] * rinv[i] + X[g];
            }
        }
    }
}

// ---------------------------------------------------------------------------
extern "C" void kernel_launch(void* const* d_in, const int* in_sizes, int n_in,
                              void* d_out, int out_size, void* d_ws, size_t ws_size,
                              hipStream_t stream) {
    const float* x  = (const float*)d_in[0];
    const float* Wq = (const float*)d_in[1];
    const float* bq = (const float*)d_in[2];
    const float* Wk = (const float*)d_in[3];
    const float* bk = (const float*)d_in[4];
    const float* Wv = (const float*)d_in[5];
    const float* bv = (const float*)d_in[6];
    float* out = (float*)d_out;
    char* ws = (char*)d_ws;

    bf16_t* Wb    = (bf16_t*)(ws);
    float*  biasc = (float*)(ws + 1572864);
    bf16_t* Xb    = (bf16_t*)(ws + 1579008);
    bf16_t* Qb    = (bf16_t*)(ws + 18356224);
    bf16_t* Kb    = (bf16_t*)(ws + 35133440);
    bf16_t* Vt    = (bf16_t*)(ws + 51910656);
    // total ws use: 68,687,872 B

    convert_in<<<4864, 256, 0, stream>>>(x, Wq, Wk, Wv, bq, bk, bv, Xb, Wb, biasc);
    qkv_gemm<<<1536, 256, 0, stream>>>(Xb, Wb, biasc, Qb, Kb, Vt);

    hipFuncSetAttribute(reinterpret_cast<const void*>(flash_attn_v4),
                        hipFuncAttributeMaxDynamicSharedMemorySize, FLASH_LDS);
    flash_attn_v4<<<256, 512, FLASH_LDS, stream>>>(Qb, Kb, Vt, x, out);
}

// Round 6
// 235.284 us; speedup vs baseline: 1.0814x; 1.0814x over previous
//
#include <hip/hip_runtime.h>
#include <hip/hip_bf16.h>

// B=8, S=2048, C=512 single-head attention + residual, fp32 I/O.
// out = softmax(QK^T) V + x,  Q/K/V = x@W^T + b  (no 1/sqrt(dk)).
//
// Round 6:
//  - qkv_gemm: reverted to round-4 version (direct Q/K stores; round-5's
//    LDS-transpose epilogue for Q/K cost ~12 us).
//  - flash_attn_v5: v3 structure (wave = 16q x 32keys QK^T, 64q x 64d PV,
//    no-max-shift softmax) with:
//      * V streamed from global (L2, batch-pinned per XCD) as registers,
//        prefetched pre-barrier -> Vs LDS buffer + its DMA + reads deleted
//      * Ks and Ps double-buffered -> ONE barrier per 64-key iter
//    Register budget kept at v3 level (qf 64 + o 64; v4's 128-VGPR Q spilled).
//
// ws layout (total 68,687,872 B):
//   Wb    bf16 [1536][512]              @ 0
//   biasc f32  [1536]                   @ 1,572,864
//   Xb    bf16 [16384][512]             @ 1,579,008
//   Qb    bf16 [16384][512]             @ 18,356,224
//   Kb    bf16 [16384][512]             @ 35,133,440
//   Vt    bf16 [8][512][2048]           @ 51,910,656

typedef __bf16 bf16_t;
typedef bf16_t bf16x8 __attribute__((ext_vector_type(8)));
typedef float floatx4 __attribute__((ext_vector_type(4)));

#define MFMA16(a, b, c) __builtin_amdgcn_mfma_f32_16x16x32_bf16((a), (b), (c), 0, 0, 0)
// Ks 2x65536 + Ps 2x9216 + lpart 512
#define FLASH_LDS 150016

__device__ __forceinline__ void gload16(const void* g, void* l) {
    __builtin_amdgcn_global_load_lds((const __attribute__((address_space(1))) void*)g,
                                     (__attribute__((address_space(3))) void*)l, 16, 0, 0);
}

__device__ __forceinline__ float wave16_sum(float v) {
    v += __shfl_xor(v, 1);
    v += __shfl_xor(v, 2);
    v += __shfl_xor(v, 4);
    v += __shfl_xor(v, 8);
    return v;
}

// ---------------------------------------------------------------------------
// Kernel 1: convert X -> bf16 (blocks 0..4095), W/b -> bf16/f32 (4096..4863).
// ---------------------------------------------------------------------------
__global__ void convert_in(const float* __restrict__ X,
                           const float* __restrict__ Wq, const float* __restrict__ Wk,
                           const float* __restrict__ Wv, const float* __restrict__ bq,
                           const float* __restrict__ bk, const float* __restrict__ bv,
                           bf16_t* __restrict__ Xb, bf16_t* __restrict__ Wb,
                           float* __restrict__ biasc) {
    int bid = blockIdx.x, tid = threadIdx.x;
    if (bid < 4096) {
        size_t e0 = ((size_t)bid * 256 + tid) * 8;
        float4 f0 = *(const float4*)(X + e0);
        float4 f1 = *(const float4*)(X + e0 + 4);
        bf16x8 o;
        o[0] = (bf16_t)f0.x; o[1] = (bf16_t)f0.y; o[2] = (bf16_t)f0.z; o[3] = (bf16_t)f0.w;
        o[4] = (bf16_t)f1.x; o[5] = (bf16_t)f1.y; o[6] = (bf16_t)f1.z; o[7] = (bf16_t)f1.w;
        *(bf16x8*)(Xb + e0) = o;
    } else {
        int idx = (bid - 4096) * 256 + tid;       // [0, 196608)
        int e0 = idx * 4;
        int row = e0 >> 9, c = e0 & 511;
        const float* src;
        if (row < 512)       src = Wq + row * 512;
        else if (row < 1024) src = Wk + (row - 512) * 512;
        else                 src = Wv + (row - 1024) * 512;
        float4 v = *(const float4*)(src + c);
        Wb[e0 + 0] = (bf16_t)v.x;
        Wb[e0 + 1] = (bf16_t)v.y;
        Wb[e0 + 2] = (bf16_t)v.z;
        Wb[e0 + 3] = (bf16_t)v.w;
        if (idx < 1536) {
            float b;
            if (idx < 512)       b = bq[idx];
            else if (idx < 1024) b = bk[idx - 512];
            else                 b = bv[idx - 1024];
            biasc[idx] = b;
        }
    }
}

// ---------------------------------------------------------------------------
// Kernel 2: QKV GEMM, C[16384][1536] = Xb * Wb^T + bias. (round-4 version)
// ---------------------------------------------------------------------------
__global__ __launch_bounds__(256, 2)
void qkv_gemm(const bf16_t* __restrict__ Xb, const bf16_t* __restrict__ Wb,
              const float* __restrict__ biasc, bf16_t* __restrict__ Q,
              bf16_t* __restrict__ K, bf16_t* __restrict__ Vt) {
    __shared__ int4 smem4[2560];          // 40960 B
    char* As = (char*)smem4;              // 16384 B: 128 rows x 8 chunks(16B)
    char* Bs = (char*)smem4 + 16384;      // 16384 B
    char* Vtile = (char*)smem4;           // 33792 B (reused after barrier)

    const int tid = threadIdx.x;
    const int l = tid & 63, w = tid >> 6;
    const int lane16 = l & 15, lq = l >> 4;
    const int klo = lane16 & 7;
    const int m0 = (blockIdx.x & 127) << 7;
    const int n0 = (blockIdx.x >> 7) << 7;
    const int wm = (w >> 1) << 6, wn = (w & 1) << 6;
    const int srow = l >> 3;
    const int sc8 = (l & 7) ^ srow;

    floatx4 acc[4][4];
#pragma unroll
    for (int a = 0; a < 4; ++a)
#pragma unroll
        for (int bb = 0; bb < 4; ++bb) acc[a][bb] = (floatx4){0.f, 0.f, 0.f, 0.f};

    for (int it = 0; it < 8; ++it) {
        __syncthreads();
#pragma unroll
        for (int j = 0; j < 4; ++j) {
            int seg = j * 4 + w;
            int row = seg * 8 + srow;
            gload16(Xb + (size_t)(m0 + row) * 512 + it * 64 + sc8 * 8, As + seg * 1024);
            gload16(Wb + (size_t)(n0 + row) * 512 + it * 64 + sc8 * 8, Bs + seg * 1024);
        }
        __syncthreads();
#pragma unroll
        for (int kst = 0; kst < 2; ++kst) {
            bf16x8 afr[4], bfr[4];
#pragma unroll
            for (int mt = 0; mt < 4; ++mt)
                afr[mt] = *(const bf16x8*)(As + (wm + mt * 16 + lane16) * 128 +
                                           ((kst * 4 + lq) ^ klo) * 16);
#pragma unroll
            for (int nt = 0; nt < 4; ++nt)
                bfr[nt] = *(const bf16x8*)(Bs + (wn + nt * 16 + lane16) * 128 +
                                           ((kst * 4 + lq) ^ klo) * 16);
#pragma unroll
            for (int mt = 0; mt < 4; ++mt)
#pragma unroll
                for (int nt = 0; nt < 4; ++nt)
                    acc[mt][nt] = MFMA16(afr[mt], bfr[nt], acc[mt][nt]);
        }
    }

    float bias_v[4];
#pragma unroll
    for (int nt = 0; nt < 4; ++nt) bias_v[nt] = biasc[n0 + wn + nt * 16 + lane16];

    if (n0 < 1024) {
        bf16_t* Dst = (n0 < 512) ? Q : K;
        const int coff = (n0 < 512 ? n0 : n0 - 512) + wn;
#pragma unroll
        for (int mt = 0; mt < 4; ++mt)
#pragma unroll
            for (int nt = 0; nt < 4; ++nt)
#pragma unroll
                for (int i = 0; i < 4; ++i) {
                    int rowM = m0 + wm + mt * 16 + lq * 4 + i;
                    Dst[(size_t)rowM * 512 + coff + nt * 16 + lane16] =
                        (bf16_t)(acc[mt][nt][i] + bias_v[nt]);
                }
    } else {
        __syncthreads();
#pragma unroll
        for (int mt = 0; mt < 4; ++mt)
#pragma unroll
            for (int nt = 0; nt < 4; ++nt)
#pragma unroll
                for (int i = 0; i < 4; ++i) {
                    int dl = wn + nt * 16 + lane16;
                    int sl = wm + mt * 16 + lq * 4 + i;
                    *(bf16_t*)(Vtile + dl * 264 + sl * 2) =
                        (bf16_t)(acc[mt][nt][i] + bias_v[nt]);
                }
        __syncthreads();
        const int bb = m0 >> 11, s0 = m0 & 2047, dbase = n0 - 1024;
#pragma unroll
        for (int j = 0; j < 8; ++j) {
            int slot = j * 256 + tid;
            int dd = slot >> 4, c = slot & 15;
            *(int4*)(Vt + (size_t)(bb * 512 + dbase + dd) * 2048 + s0 + c * 8) =
                *(const int4*)(Vtile + dd * 264 + c * 16);
        }
    }
}

// ---------------------------------------------------------------------------
// Kernel 3: flash attention v5 + residual. 256 blocks (b = bid&7 -> XCD
// affinity), 512 threads = 8 waves. Block = 64 q-rows, iter = 64 keys.
//  QK^T: wave (qg = w>>1, h = w&1) computes S[16 q][32-key half], Q in regs,
//        K frags from swizzled LDS (async-staged, DOUBLE-buffered).
//  softmax: p = exp(s) (no max shift), P -> Ps[cur] (144 B stride, dbuf).
//  PV:   wave w owns d-slice w*64..+64 for all 64 q rows; V frags loaded
//        DIRECTLY FROM GLOBAL (L2-resident, prefetched before the barrier,
//        reused x4 across q-groups in-register).
//  ONE barrier per iter: drains K_{t+1} DMA + vb prefetch, publishes P.
// ---------------------------------------------------------------------------
__global__ __launch_bounds__(512, 2)
void flash_attn_v5(const bf16_t* __restrict__ Q, const bf16_t* __restrict__ K,
                   const bf16_t* __restrict__ Vt, const float* __restrict__ X,
                   float* __restrict__ Out) {
    extern __shared__ char smem[];
    char* Ks0 = smem;                  // 2 x 65536: 64 keys x 64 chunks, swizzled
    char* Ps0 = smem + 131072;         // 2 x 9216: 64 rows x 144 B
    float* lpart = (float*)(smem + 149504);   // 64 rows x 2 halves

    const int tid = threadIdx.x;
    const int l = tid & 63, w = tid >> 6;
    const int lane16 = l & 15, lq = l >> 4;
    const int qg = w >> 1, h = w & 1;          // QK^T role
    const int dbase = w << 6;                  // PV d-slice
    const int b = blockIdx.x & 7;
    const int q0 = (blockIdx.x >> 3) << 6;

    const bf16_t* Kbase = K + (size_t)b * 2048 * 512;
    const bf16_t* Vbase = Vt + (size_t)b * 512 * 2048;

    // stage K_0 into buffer 0
#pragma unroll
    for (int j = 0; j < 8; ++j) {
        int seg = j * 8 + w;
        int c = (l & ~7) | ((l & 7) ^ (seg & 7));
        gload16(Kbase + (size_t)seg * 512 + c * 8, Ks0 + seg * 1024);
    }

    // Q fragments: A[m=lane16][k=lq*8+...] for rows q0+qg*16..+16
    bf16x8 qf[16];
    const bf16_t* Qrow = Q + (size_t)(b * 2048 + q0 + qg * 16 + lane16) * 512 + lq * 8;
#pragma unroll
    for (int kst = 0; kst < 16; ++kst) qf[kst] = *(const bf16x8*)(Qrow + kst * 32);

    floatx4 o[16];                     // [qgi][dg]
#pragma unroll
    for (int t = 0; t < 16; ++t) o[t] = (floatx4){0.f, 0.f, 0.f, 0.f};
    float lsum[4] = {0.f, 0.f, 0.f, 0.f};
    const float L2E = 1.4426950408889634f;

    __syncthreads();   // K_0 staged

    for (int kt = 0; kt < 32; ++kt) {
        const int cur = kt & 1;
        char* Ks = Ks0 + cur * 65536;
        char* Ps = Ps0 + cur * 9216;

        // issue K_{kt+1} DMA into the other buffer (drained at this iter's
        // barrier; overlaps QK^T + softmax). PV never reads Ks -> no race.
        if (kt < 31) {
            char* Kn = Ks0 + (1 - cur) * 65536;
            const bf16_t* Ksrc = Kbase + (size_t)(kt + 1) * 64 * 512;
#pragma unroll
            for (int j = 0; j < 8; ++j) {
                int seg = j * 8 + w;
                int c = (l & ~7) | ((l & 7) ^ (seg & 7));
                gload16(Ksrc + (size_t)seg * 512 + c * 8, Kn + seg * 1024);
            }
        }

        // ---- QK^T: 16 q rows x 32 keys (this wave's half), k=512 ----
        floatx4 scA[2], scB[2];
#pragma unroll
        for (int g = 0; g < 2; ++g) {
            scA[g] = (floatx4){0.f, 0.f, 0.f, 0.f};
            scB[g] = (floatx4){0.f, 0.f, 0.f, 0.f};
        }
#pragma unroll
        for (int kst = 0; kst < 16; kst += 2) {
#pragma unroll
            for (int g = 0; g < 2; ++g) {
                int key = h * 32 + g * 16 + lane16;
                int i0 = kst * 4 + lq;
                int i1 = i0 + 4;
                int p0 = (i0 & ~7) | ((i0 & 7) ^ (key & 7));
                int p1 = (i1 & ~7) | ((i1 & 7) ^ (key & 7));
                bf16x8 kb0 = *(const bf16x8*)(Ks + key * 1024 + p0 * 16);
                bf16x8 kb1 = *(const bf16x8*)(Ks + key * 1024 + p1 * 16);
                scA[g] = MFMA16(qf[kst], kb0, scA[g]);
                scB[g] = MFMA16(qf[kst + 1], kb1, scB[g]);
            }
        }

        // ---- softmax (no max shift): p = exp(s), write P, accumulate l ----
#pragma unroll
        for (int g = 0; g < 2; ++g) {
            int keyc = h * 32 + g * 16 + lane16;
#pragma unroll
            for (int i = 0; i < 4; ++i) {
                float p = __builtin_exp2f((scA[g][i] + scB[g][i]) * L2E);
                lsum[i] += p;
                *(bf16_t*)(Ps + (qg * 16 + lq * 4 + i) * 144 + keyc * 2) = (bf16_t)p;
            }
        }

        // ---- prefetch V fragments from global (L2); drained by barrier ----
        bf16x8 vb[2][4];
#pragma unroll
        for (int kk = 0; kk < 2; ++kk)
#pragma unroll
            for (int dg = 0; dg < 4; ++dg) {
                int d = dbase + dg * 16 + lane16;
                vb[kk][dg] = *(const bf16x8*)(Vbase + (size_t)d * 2048 +
                                              kt * 64 + kk * 32 + lq * 8);
            }

        __syncthreads();   // drains K_{t+1} DMA + vb; P visible

        // ---- PV: O[64 q x 64 d slice] += P[64x64] * V^T ----
#pragma unroll
        for (int kk = 0; kk < 2; ++kk) {
            bf16x8 pa[4];
#pragma unroll
            for (int qgi = 0; qgi < 4; ++qgi)
                pa[qgi] = *(const bf16x8*)(Ps + (qgi * 16 + lane16) * 144 + kk * 64 + lq * 16);
#pragma unroll
            for (int dg = 0; dg < 4; ++dg)
#pragma unroll
                for (int qgi = 0; qgi < 4; ++qgi)
                    o[qgi * 4 + dg] = MFMA16(pa[qgi], vb[kk][dg], o[qgi * 4 + dg]);
        }
        // no second barrier: next iter uses the other Ks/Ps buffers, and
        // barrier collectivity guarantees this iter's Ps reads complete
        // before any wave reaches the iter-after-next's Ps writes.
    }

    // epilogue: reduce l across lane16 and key-halves, normalize, + residual
#pragma unroll
    for (int i = 0; i < 4; ++i) {
        float s = wave16_sum(lsum[i]);
        if (lane16 == 0) lpart[(qg * 16 + lq * 4 + i) * 2 + h] = s;
    }
    __syncthreads();

#pragma unroll
    for (int qgi = 0; qgi < 4; ++qgi) {
        float rinv[4];
#pragma unroll
        for (int i = 0; i < 4; ++i) {
            int row = qgi * 16 + lq * 4 + i;
            rinv[i] = 1.0f / (lpart[row * 2] + lpart[row * 2 + 1]);
        }
#pragma unroll
        for (int dg = 0; dg < 4; ++dg) {
            int d = dbase + dg * 16 + lane16;
#pragma unroll
            for (int i = 0; i < 4; ++i) {
                int row = q0 + qgi * 16 + lq * 4 + i;
                size_t g = (size_t)(b * 2048 + row) * 512 + d;
                Out[g] = o[qgi * 4 + dg][i] * rinv[i] + X[g];
            }
        }
    }
}

// ---------------------------------------------------------------------------
extern "C" void kernel_launch(void* const* d_in, const int* in_sizes, int n_in,
                              void* d_out, int out_size, void* d_ws, size_t ws_size,
                              hipStream_t stream) {
    const float* x  = (const float*)d_in[0];
    const float* Wq = (const float*)d_in[1];
    const float* bq = (const float*)d_in[2];
    const float* Wk = (const float*)d_in[3];
    const float* bk = (const float*)d_in[4];
    const float* Wv = (const float*)d_in[5];
    const float* bv = (const float*)d_in[6];
    float* out = (float*)d_out;
    char* ws = (char*)d_ws;

    bf16_t* Wb    = (bf16_t*)(ws);
    float*  biasc = (float*)(ws + 1572864);
    bf16_t* Xb    = (bf16_t*)(ws + 1579008);
    bf16_t* Qb    = (bf16_t*)(ws + 18356224);
    bf16_t* Kb    = (bf16_t*)(ws + 35133440);
    bf16_t* Vt    = (bf16_t*)(ws + 51910656);
    // total ws use: 68,687,872 B

    convert_in<<<4864, 256, 0, stream>>>(x, Wq, Wk, Wv, bq, bk, bv, Xb, Wb, biasc);
    qkv_gemm<<<1536, 256, 0, stream>>>(Xb, Wb, biasc, Qb, Kb, Vt);

    hipFuncSetAttribute(reinterpret_cast<const void*>(flash_attn_v5),
                        hipFuncAttributeMaxDynamicSharedMemorySize, FLASH_LDS);
    flash_attn_v5<<<256, 512, FLASH_LDS, stream>>>(Qb, Kb, Vt, x, out);
}